// Round 6
// baseline (60051.294 us; speedup 1.0000x reference)
//
#include <hip/hip_runtime.h>
#include <stdint.h>
#include <stddef.h>

#define T_SEQ 8192
#define HDIM  2048
#define NB    256
#define NT    512
#define DYN_LDS_BYTES 131072   // 16 float4-rows x 512 threads x 16B

// workspace layout (bytes):
//   [0,4096)       : 256 per-WG flags, one int per 16B
//   [4096,20480)   : hbuf float[2][2048]
//   [20480,53248)  : feat float[8192]
//   [53248,61440)  : hid  float[2048]
#define WS_ZERO_DWORDS 16384   // zero first 64KB

__global__ void init_ws_kernel(uint32_t* ws) {
    int i = blockIdx.x * blockDim.x + threadIdx.x;
    if (i < WS_ZERO_DWORDS) ws[i] = 0u;
}

__device__ __forceinline__ float sigm(float xv) { return 1.0f / (1.0f + expf(-xv)); }

typedef unsigned long long u64;

// R2-R5 lesson: the allocator grants this kernel ~100-128 VGPRs at 512 thr and
// spills anything above (scratch -> 512 GB/run L2/L3 restream = 55-93 ms).
// So the design fits the budget instead of fighting it: 64 weight floats in
// VGPRs (asm-pinned vs remat) + 64 weight floats in LDS fp32. Demand ~110.
__global__ void __launch_bounds__(NT)
policy_persistent(
    const float* __restrict__ x,      // (8192,3)
    const float* __restrict__ ldist,  // scalar
    const float* __restrict__ lhead,  // scalar
    const float* __restrict__ W_ih,   // (8192,3)
    const float* __restrict__ W_hh,   // (8192,2048)
    const float* __restrict__ b_ih,   // (8192)
    const float* __restrict__ b_hh,   // (8192)
    const float* __restrict__ W1,     // (2048,8192)
    const float* __restrict__ b1,     // (2048)
    const float* __restrict__ W2,     // (4,2048)
    const float* __restrict__ b2,     // (4)
    float* __restrict__ out,          // (4)
    int*   __restrict__ flags,        // 256 flags, stride 4 ints (16B)
    float* __restrict__ hbuf,         // 2*2048
    float* __restrict__ feat,         // 8192
    float* __restrict__ hid)          // 2048
{
    const int w    = blockIdx.x;
    const int tid  = threadIdx.x;
    const int v    = tid >> 6;             // wave 0..7
    const int lane = tid & 63;
    const int r    = v * 4 + (lane >> 4);  // row within WG block, 0..31
    const int g    = lane & 15;            // 128-col chunk, 0..15
    const int q    = r >> 3;               // gate (i,f,g,o)
    const int p    = r & 7;                // h offset within this WG's 8

    // dynamic LDS: weight store w[j][tid] (j=0..15 float4 rows); aliased as
    // feat_lds (32KB) during the MLP phase (weights dead by then).
    extern __shared__ float4 dynw[];

    __shared__ float4 h_lds4[16 * 33];   // chunk c at float4 index c*33 (pad 1)
    __shared__ float  gates_lds[128];
    __shared__ float  c_lds[8];
    __shared__ float  red_lds[8];

    const int row = q * HDIM + 8 * w + p;  // global gate row in [0,8192)

    // ---- weight prologue: 128 floats/lane = 16 float4 to VGPR + 16 to LDS ----
    float4 wreg[16];
    {
        const float4* wp = (const float4*)(W_hh + (size_t)row * HDIM) + g * 32;
#pragma unroll
        for (int i = 0; i < 16; ++i) {
            wreg[i] = wp[i];
            asm volatile("" : "+v"(wreg[i].x), "+v"(wreg[i].y),
                              "+v"(wreg[i].z), "+v"(wreg[i].w));
        }
#pragma unroll
        for (int j = 0; j < 16; ++j)
            dynw[j * NT + tid] = wp[16 + j];   // w[j][tid]: wave-consecutive
    }
    const float brow = b_ih[row] + b_hh[row];
    const float wih0 = W_ih[row * 3 + 0];
    const float wih1 = W_ih[row * 3 + 1];
    const float wih2 = W_ih[row * 3 + 2];
    if (tid < 8) c_lds[tid] = 0.0f;

    // ---- sequential recurrence + action step (t == T_SEQ) ----
    for (int t = 0; t <= T_SEQ; ++t) {
        // prefetch x[t] BEFORE the spin — independent of h, hides latency
        float xt0 = 0.f, xt1 = 0.f, xt2 = 0.f;
        if (t < T_SEQ) { xt0 = x[3 * t]; xt1 = x[3 * t + 1]; xt2 = x[3 * t + 2]; }

        // phase 0: wait until every WG has published step t-1 (flag[w] >= t)
        if (tid < 256) {
            while (__hip_atomic_load(&flags[tid * 4], __ATOMIC_RELAXED,
                                     __HIP_MEMORY_SCOPE_AGENT) < t)
                __builtin_amdgcn_s_sleep(1);
        }
        __syncthreads();

        // phase 1: stage h_{t-1} into padded LDS, one float4 per thread
        {
            const u64* h64 = (const u64*)(hbuf + (((t + 1) & 1) ? HDIM : 0));
            u64 a0 = __hip_atomic_load(h64 + 2 * tid,     __ATOMIC_RELAXED,
                                       __HIP_MEMORY_SCOPE_AGENT);
            u64 a1 = __hip_atomic_load(h64 + 2 * tid + 1, __ATOMIC_RELAXED,
                                       __HIP_MEMORY_SCOPE_AGENT);
            float2 f0 = *(float2*)&a0;
            float2 f1 = *(float2*)&a1;
            h_lds4[(tid >> 5) * 33 + (tid & 31)] = make_float4(f0.x, f0.y, f1.x, f1.y);
        }
        __syncthreads();

        // phase 2: partial GEMV — reg half (cols g*128..+63) + LDS half (+64..+127)
        float acc = 0.0f;
        {
            const float4* hbreg = &h_lds4[g * 33];
#pragma unroll
            for (int i = 0; i < 16; ++i) {
                float4 hv = hbreg[i];
                float4 wv = wreg[i];
                acc = fmaf(wv.x, hv.x, acc); acc = fmaf(wv.y, hv.y, acc);
                acc = fmaf(wv.z, hv.z, acc); acc = fmaf(wv.w, hv.w, acc);
            }
            const float4* hblds = &h_lds4[g * 33 + 16];
            const float4* wl = dynw + tid;
#pragma unroll
            for (int j = 0; j < 16; ++j) {
                float4 hv = hblds[j];
                float4 wv = wl[j * NT];
                acc = fmaf(wv.x, hv.x, acc); acc = fmaf(wv.y, hv.y, acc);
                acc = fmaf(wv.z, hv.z, acc); acc = fmaf(wv.w, hv.w, acc);
            }
        }
        // reduce over the 16 col-chunks (lane bits 0..3)
        acc += __shfl_xor(acc, 1, 64);
        acc += __shfl_xor(acc, 2, 64);
        acc += __shfl_xor(acc, 4, 64);
        acc += __shfl_xor(acc, 8, 64);

        if (t < T_SEQ) {
            if (g == 0) {
                float xg = wih0 * xt0 + wih1 * xt1 + wih2 * xt2;
                gates_lds[q * 8 + p] = acc + brow + xg;
            }
            __syncthreads();
            if (v == 0) {
                if (lane < 8) {
                    float ig = gates_lds[lane],      fg = gates_lds[8 + lane];
                    float gg = gates_lds[16 + lane], og = gates_lds[24 + lane];
                    float c0 = c_lds[lane];
                    float cn = sigm(fg) * c0 + sigm(ig) * tanhf(gg);
                    float hn = sigm(og) * tanhf(cn);
                    c_lds[lane] = cn;
                    __hip_atomic_store(&hbuf[(t & 1) * HDIM + 8 * w + lane], hn,
                                       __ATOMIC_RELAXED, __HIP_MEMORY_SCOPE_AGENT);
                }
                __threadfence();   // drain the h stores
                if (lane == 0)
                    __hip_atomic_store(&flags[w * 4], t + 1, __ATOMIC_RELAXED,
                                       __HIP_MEMORY_SCOPE_AGENT);
            }
        } else {
            // 4 batched action rollouts from (h_n, c_n); W_hh@h_n already in acc
            const float ld0 = *ldist, lh0 = *lhead;
            if (g == 0) {
#pragma unroll
                for (int a = 0; a < 4; ++a) {
                    float xg = wih0 * ld0 + wih1 * lh0 + wih2 * (float)a;
                    gates_lds[a * 32 + q * 8 + p] = acc + brow + xg;
                }
            }
            __syncthreads();
            if (v == 0) {
                if (lane < 8) {
                    float c0 = c_lds[lane];
#pragma unroll
                    for (int a = 0; a < 4; ++a) {
                        float ig = gates_lds[a * 32 + lane];
                        float fg = gates_lds[a * 32 + 8 + lane];
                        float gg = gates_lds[a * 32 + 16 + lane];
                        float og = gates_lds[a * 32 + 24 + lane];
                        float cn = sigm(fg) * c0 + sigm(ig) * tanhf(gg);
                        float hn = sigm(og) * tanhf(cn);
                        __hip_atomic_store(&feat[a * HDIM + 8 * w + lane], hn,
                                           __ATOMIC_RELAXED, __HIP_MEMORY_SCOPE_AGENT);
                    }
                }
                __threadfence();
                if (lane == 0)
                    __hip_atomic_store(&flags[w * 4], T_SEQ + 1, __ATOMIC_RELAXED,
                                       __HIP_MEMORY_SCOPE_AGENT);
            }
        }
    }

    // ---- MLP layer 1: hid = relu(W1 @ feat + b1), 8 rows per WG ----
    // feat_lds aliases the (now dead) weight LDS region.
    float* feat_lds = (float*)dynw;
    if (tid < 256) {
        while (__hip_atomic_load(&flags[tid * 4], __ATOMIC_RELAXED,
                                 __HIP_MEMORY_SCOPE_AGENT) < T_SEQ + 1)
            __builtin_amdgcn_s_sleep(1);
    }
    __syncthreads();
    {
        const u64* f64 = (const u64*)feat;
        u64* fl64 = (u64*)feat_lds;
#pragma unroll
        for (int k = 0; k < 8; ++k) {
            u64 a = __hip_atomic_load(f64 + k * NT + tid, __ATOMIC_RELAXED,
                                      __HIP_MEMORY_SCOPE_AGENT);
            fl64[k * NT + tid] = a;
        }
    }
    __syncthreads();
    const float4* flds4 = (const float4*)feat_lds;
    for (int rr = 0; rr < 8; ++rr) {
        const int hrow = 8 * w + rr;
        const float4* Wrow4 = (const float4*)(W1 + (size_t)hrow * 4 * HDIM);
        float pacc = 0.0f;
#pragma unroll
        for (int s = 0; s < 4; ++s) {
            int idx = s * NT + tid;
            float4 wv = Wrow4[idx];
            float4 fv = flds4[idx];
            pacc = fmaf(wv.x, fv.x, pacc); pacc = fmaf(wv.y, fv.y, pacc);
            pacc = fmaf(wv.z, fv.z, pacc); pacc = fmaf(wv.w, fv.w, pacc);
        }
#pragma unroll
        for (int m = 1; m < 64; m <<= 1) pacc += __shfl_xor(pacc, m, 64);
        if (lane == 0) red_lds[v] = pacc;
        __syncthreads();
        if (tid == 0) {
            float s = b1[hrow];
#pragma unroll
            for (int k = 0; k < 8; ++k) s += red_lds[k];
            __hip_atomic_store(&hid[hrow], fmaxf(s, 0.0f), __ATOMIC_RELAXED,
                               __HIP_MEMORY_SCOPE_AGENT);
        }
        __syncthreads();
    }
    __threadfence();
    if (tid == 0)
        __hip_atomic_store(&flags[w * 4], T_SEQ + 2, __ATOMIC_RELAXED,
                           __HIP_MEMORY_SCOPE_AGENT);

    // ---- output layer: WG 0 only ----
    if (w == 0) {
        if (tid < 256) {
            while (__hip_atomic_load(&flags[tid * 4], __ATOMIC_RELAXED,
                                     __HIP_MEMORY_SCOPE_AGENT) < T_SEQ + 2)
                __builtin_amdgcn_s_sleep(1);
        }
        __syncthreads();
        float hv4[4];
        {
            const u64* h64 = (const u64*)hid;
            u64 a0 = __hip_atomic_load(h64 + 2 * tid,     __ATOMIC_RELAXED,
                                       __HIP_MEMORY_SCOPE_AGENT);
            u64 a1 = __hip_atomic_load(h64 + 2 * tid + 1, __ATOMIC_RELAXED,
                                       __HIP_MEMORY_SCOPE_AGENT);
            float2 f0 = *(float2*)&a0;
            float2 f1 = *(float2*)&a1;
            hv4[0] = f0.x; hv4[1] = f0.y; hv4[2] = f1.x; hv4[3] = f1.y;
        }
#pragma unroll
        for (int o = 0; o < 4; ++o) {
            float pv = 0.0f;
#pragma unroll
            for (int k = 0; k < 4; ++k)
                pv = fmaf(W2[o * HDIM + tid * 4 + k], hv4[k], pv);
#pragma unroll
            for (int m = 1; m < 64; m <<= 1) pv += __shfl_xor(pv, m, 64);
            if (lane == 0) red_lds[v] = pv;
            __syncthreads();
            if (tid == 0) {
                float s = b2[o];
#pragma unroll
                for (int k = 0; k < 8; ++k) s += red_lds[k];
                out[o] = s;
            }
            __syncthreads();
        }
    }
}

extern "C" void kernel_launch(void* const* d_in, const int* in_sizes, int n_in,
                              void* d_out, int out_size, void* d_ws, size_t ws_size,
                              hipStream_t stream) {
    const float* x     = (const float*)d_in[0];
    const float* ldist = (const float*)d_in[1];
    const float* lhead = (const float*)d_in[2];
    const float* W_ih  = (const float*)d_in[3];
    const float* W_hh  = (const float*)d_in[4];
    const float* b_ih  = (const float*)d_in[5];
    const float* b_hh  = (const float*)d_in[6];
    const float* W1    = (const float*)d_in[7];
    const float* b1    = (const float*)d_in[8];
    const float* W2    = (const float*)d_in[9];
    const float* b2    = (const float*)d_in[10];
    float* out = (float*)d_out;

    uint8_t* wsb = (uint8_t*)d_ws;
    int*   flags = (int*)wsb;
    float* hbuf  = (float*)(wsb + 4096);
    float* feat  = (float*)(wsb + 20480);
    float* hid   = (float*)(wsb + 53248);

    // allow >64KB dynamic LDS (host-side attribute set, not a stream op)
    static int attr_done = 0;
    if (!attr_done) {
        hipFuncSetAttribute((const void*)policy_persistent,
                            hipFuncAttributeMaxDynamicSharedMemorySize,
                            DYN_LDS_BYTES);
        attr_done = 1;
    }

    // zero flags / hbuf / feat / hid (ws is poisoned 0xAA before every launch)
    hipLaunchKernelGGL(init_ws_kernel, dim3(64), dim3(256), 0, stream, (uint32_t*)d_ws);

    void* args[] = {
        (void*)&x, (void*)&ldist, (void*)&lhead, (void*)&W_ih, (void*)&W_hh,
        (void*)&b_ih, (void*)&b_hh, (void*)&W1, (void*)&b1, (void*)&W2, (void*)&b2,
        (void*)&out, (void*)&flags, (void*)&hbuf, (void*)&feat, (void*)&hid
    };
    hipError_t e = hipLaunchCooperativeKernel((void*)policy_persistent,
                                              dim3(NB), dim3(NT), args,
                                              DYN_LDS_BYTES, stream);
    if (e != hipSuccess) {
        // fallback: normal launch — ~140KB LDS/WG forces 1 WG/CU, grid == #CUs,
        // so all 256 WGs are co-resident anyway.
        hipLaunchKernelGGL(policy_persistent, dim3(NB), dim3(NT), DYN_LDS_BYTES,
                           stream,
                           x, ldist, lhead, W_ih, W_hh, b_ih, b_hh, W1, b1, W2, b2,
                           out, flags, hbuf, feat, hid);
    }
}

// Round 7
// 59977.216 us; speedup vs baseline: 1.0012x; 1.0012x over previous
//
#include <hip/hip_runtime.h>
#include <stdint.h>
#include <stddef.h>

#define T_SEQ 8192
#define HDIM  2048
#define NB    256
#define NT    512

#define WROWS_STATIC  6                    // float4 weight rows in static LDS
#define WROWS_DYN     10                   // float4 weight rows in dynamic LDS
#define DYN_LDS_BYTES (WROWS_DYN * NT * 16)   // 81920 B

// workspace layout (bytes):
//   [0,4096)       : 256 per-WG flags, one int per 16B
//   [4096,20480)   : hbuf float[2][2048]
//   [20480,53248)  : feat float[8192]
//   [53248,61440)  : hid  float[2048]
#define WS_ZERO_DWORDS 16384   // zero first 64KB

__global__ void init_ws_kernel(uint32_t* ws) {
    int i = blockIdx.x * blockDim.x + threadIdx.x;
    if (i < WS_ZERO_DWORDS) ws[i] = 0u;
}

__device__ __forceinline__ float sigm(float xv) { return 1.0f / (1.0f + expf(-xv)); }

typedef unsigned long long u64;

// R2-R6 lesson: the backend's VGPR budget = f(occupancy implied by *static*
// LDS).  9KB static -> granted 80; 42KB -> 100; here 58KB static implies max
// 2 WG/CU at compile time -> budget ~128.  Demand = 64 weight VGPRs (asm-
// pinned) + ~40 working = ~104 < 128 -> first spill-free configuration.
// Dynamic LDS (invisible to the heuristic) holds 10 more weight rows; runtime
// total 140KB -> 1 WG/CU.
__global__ void __launch_bounds__(NT)
policy_persistent(
    const float* __restrict__ x,      // (8192,3)
    const float* __restrict__ ldist,  // scalar
    const float* __restrict__ lhead,  // scalar
    const float* __restrict__ W_ih,   // (8192,3)
    const float* __restrict__ W_hh,   // (8192,2048)
    const float* __restrict__ b_ih,   // (8192)
    const float* __restrict__ b_hh,   // (8192)
    const float* __restrict__ W1,     // (2048,8192)
    const float* __restrict__ b1,     // (2048)
    const float* __restrict__ W2,     // (4,2048)
    const float* __restrict__ b2,     // (4)
    float* __restrict__ out,          // (4)
    int*   __restrict__ flags,        // 256 flags, stride 4 ints (16B)
    float* __restrict__ hbuf,         // 2*2048
    float* __restrict__ feat,         // 8192
    float* __restrict__ hid)          // 2048
{
    const int w    = blockIdx.x;
    const int tid  = threadIdx.x;
    const int v    = tid >> 6;             // wave 0..7
    const int lane = tid & 63;
    const int g    = lane & 15;            // 128-col chunk, 0..15
    const int r    = v * 4 + (lane >> 4);  // row within WG block, 0..31
    const int q    = r >> 3;               // gate (i,f,g,o)
    const int p    = r & 7;                // h offset within this WG's 8

    // static LDS: ~58KB total — this is what the occupancy heuristic sees.
    __shared__ float4 wlds_s[WROWS_STATIC * NT];  // 48KB weight rows 0..5
    __shared__ float4 h_lds4[16 * 33];            // h chunks, pad 1 float4
    __shared__ float  gates_lds[128];
    __shared__ float  c_lds[8];
    __shared__ float  red_lds[8];
    // dynamic LDS: weight rows 6..15 (80KB)
    extern __shared__ float4 wlds_d[];

    const int row = q * HDIM + 8 * w + p;  // global gate row in [0,8192)

    // ---- weight prologue: 128 floats/lane = 32 float4 ----
    //   f4[0..15]  -> VGPRs (asm pin vs rematerialization)
    //   f4[16..21] -> static LDS rows, f4[22..31] -> dynamic LDS rows
    float4 wreg[16];
    {
        const float4* wp = (const float4*)(W_hh + (size_t)row * HDIM) + g * 32;
#pragma unroll
        for (int i = 0; i < 16; ++i) {
            wreg[i] = wp[i];
            asm volatile("" : "+v"(wreg[i].x), "+v"(wreg[i].y),
                              "+v"(wreg[i].z), "+v"(wreg[i].w));
        }
#pragma unroll
        for (int j = 0; j < WROWS_STATIC; ++j)
            wlds_s[j * NT + tid] = wp[16 + j];
#pragma unroll
        for (int j = 0; j < WROWS_DYN; ++j)
            wlds_d[j * NT + tid] = wp[16 + WROWS_STATIC + j];
    }
    const float brow = b_ih[row] + b_hh[row];
    const float wih0 = W_ih[row * 3 + 0];
    const float wih1 = W_ih[row * 3 + 1];
    const float wih2 = W_ih[row * 3 + 2];
    if (tid < 8) c_lds[tid] = 0.0f;

    // ---- sequential recurrence + action step (t == T_SEQ) ----
    for (int t = 0; t <= T_SEQ; ++t) {
        // prefetch x[t] BEFORE the spin — independent of h, hides latency
        float xt0 = 0.f, xt1 = 0.f, xt2 = 0.f;
        if (t < T_SEQ) { xt0 = x[3 * t]; xt1 = x[3 * t + 1]; xt2 = x[3 * t + 2]; }

        // phase 0: wait until every WG has published step t-1 (flag[w] >= t)
        if (tid < 256) {
            while (__hip_atomic_load(&flags[tid * 4], __ATOMIC_RELAXED,
                                     __HIP_MEMORY_SCOPE_AGENT) < t)
                __builtin_amdgcn_s_sleep(1);
        }
        __syncthreads();

        // phase 1: stage h_{t-1} into padded LDS, one float4 per thread
        {
            const u64* h64 = (const u64*)(hbuf + (((t + 1) & 1) ? HDIM : 0));
            u64 a0 = __hip_atomic_load(h64 + 2 * tid,     __ATOMIC_RELAXED,
                                       __HIP_MEMORY_SCOPE_AGENT);
            u64 a1 = __hip_atomic_load(h64 + 2 * tid + 1, __ATOMIC_RELAXED,
                                       __HIP_MEMORY_SCOPE_AGENT);
            float2 f0 = *(float2*)&a0;
            float2 f1 = *(float2*)&a1;
            h_lds4[(tid >> 5) * 33 + (tid & 31)] = make_float4(f0.x, f0.y, f1.x, f1.y);
        }
        __syncthreads();

        // phase 2: partial GEMV — reg half (h f4 0..15) + LDS half (16..31)
        float acc = 0.0f;
        {
            const float4* hbreg = &h_lds4[g * 33];
#pragma unroll
            for (int i = 0; i < 16; ++i) {
                float4 hv = hbreg[i];
                float4 wv = wreg[i];
                acc = fmaf(wv.x, hv.x, acc); acc = fmaf(wv.y, hv.y, acc);
                acc = fmaf(wv.z, hv.z, acc); acc = fmaf(wv.w, hv.w, acc);
            }
            const float4* ws = wlds_s + tid;
#pragma unroll
            for (int j = 0; j < WROWS_STATIC; ++j) {
                float4 hv = hbreg[16 + j];
                float4 wv = ws[j * NT];
                acc = fmaf(wv.x, hv.x, acc); acc = fmaf(wv.y, hv.y, acc);
                acc = fmaf(wv.z, hv.z, acc); acc = fmaf(wv.w, hv.w, acc);
            }
            const float4* wd = wlds_d + tid;
#pragma unroll
            for (int j = 0; j < WROWS_DYN; ++j) {
                float4 hv = hbreg[16 + WROWS_STATIC + j];
                float4 wv = wd[j * NT];
                acc = fmaf(wv.x, hv.x, acc); acc = fmaf(wv.y, hv.y, acc);
                acc = fmaf(wv.z, hv.z, acc); acc = fmaf(wv.w, hv.w, acc);
            }
        }
        // reduce over the 16 col-chunks (lane bits 0..3)
        acc += __shfl_xor(acc, 1, 64);
        acc += __shfl_xor(acc, 2, 64);
        acc += __shfl_xor(acc, 4, 64);
        acc += __shfl_xor(acc, 8, 64);

        if (t < T_SEQ) {
            if (g == 0) {
                float xg = wih0 * xt0 + wih1 * xt1 + wih2 * xt2;
                gates_lds[q * 8 + p] = acc + brow + xg;
            }
            __syncthreads();
            if (v == 0) {
                if (lane < 8) {
                    float ig = gates_lds[lane],      fg = gates_lds[8 + lane];
                    float gg = gates_lds[16 + lane], og = gates_lds[24 + lane];
                    float c0 = c_lds[lane];
                    float cn = sigm(fg) * c0 + sigm(ig) * tanhf(gg);
                    float hn = sigm(og) * tanhf(cn);
                    c_lds[lane] = cn;
                    __hip_atomic_store(&hbuf[(t & 1) * HDIM + 8 * w + lane], hn,
                                       __ATOMIC_RELAXED, __HIP_MEMORY_SCOPE_AGENT);
                }
                __threadfence();   // drain the h stores
                if (lane == 0)
                    __hip_atomic_store(&flags[w * 4], t + 1, __ATOMIC_RELAXED,
                                       __HIP_MEMORY_SCOPE_AGENT);
            }
        } else {
            // 4 batched action rollouts from (h_n, c_n); W_hh@h_n already in acc
            const float ld0 = *ldist, lh0 = *lhead;
            if (g == 0) {
#pragma unroll
                for (int a = 0; a < 4; ++a) {
                    float xg = wih0 * ld0 + wih1 * lh0 + wih2 * (float)a;
                    gates_lds[a * 32 + q * 8 + p] = acc + brow + xg;
                }
            }
            __syncthreads();
            if (v == 0) {
                if (lane < 8) {
                    float c0 = c_lds[lane];
#pragma unroll
                    for (int a = 0; a < 4; ++a) {
                        float ig = gates_lds[a * 32 + lane];
                        float fg = gates_lds[a * 32 + 8 + lane];
                        float gg = gates_lds[a * 32 + 16 + lane];
                        float og = gates_lds[a * 32 + 24 + lane];
                        float cn = sigm(fg) * c0 + sigm(ig) * tanhf(gg);
                        float hn = sigm(og) * tanhf(cn);
                        __hip_atomic_store(&feat[a * HDIM + 8 * w + lane], hn,
                                           __ATOMIC_RELAXED, __HIP_MEMORY_SCOPE_AGENT);
                    }
                }
                __threadfence();
                if (lane == 0)
                    __hip_atomic_store(&flags[w * 4], T_SEQ + 1, __ATOMIC_RELAXED,
                                       __HIP_MEMORY_SCOPE_AGENT);
            }
        }
    }

    // ---- MLP layer 1: hid = relu(W1 @ feat + b1), 8 rows per WG ----
    // feat_lds (32KB) aliases the static weight rows (48KB, now dead).
    float* feat_lds = (float*)wlds_s;
    if (tid < 256) {
        while (__hip_atomic_load(&flags[tid * 4], __ATOMIC_RELAXED,
                                 __HIP_MEMORY_SCOPE_AGENT) < T_SEQ + 1)
            __builtin_amdgcn_s_sleep(1);
    }
    __syncthreads();
    {
        const u64* f64 = (const u64*)feat;
        u64* fl64 = (u64*)feat_lds;
#pragma unroll
        for (int k = 0; k < 8; ++k) {
            u64 a = __hip_atomic_load(f64 + k * NT + tid, __ATOMIC_RELAXED,
                                      __HIP_MEMORY_SCOPE_AGENT);
            fl64[k * NT + tid] = a;
        }
    }
    __syncthreads();
    const float4* flds4 = (const float4*)feat_lds;
    for (int rr = 0; rr < 8; ++rr) {
        const int hrow = 8 * w + rr;
        const float4* Wrow4 = (const float4*)(W1 + (size_t)hrow * 4 * HDIM);
        float pacc = 0.0f;
#pragma unroll
        for (int s = 0; s < 4; ++s) {
            int idx = s * NT + tid;
            float4 wv = Wrow4[idx];
            float4 fv = flds4[idx];
            pacc = fmaf(wv.x, fv.x, pacc); pacc = fmaf(wv.y, fv.y, pacc);
            pacc = fmaf(wv.z, fv.z, pacc); pacc = fmaf(wv.w, fv.w, pacc);
        }
#pragma unroll
        for (int m = 1; m < 64; m <<= 1) pacc += __shfl_xor(pacc, m, 64);
        if (lane == 0) red_lds[v] = pacc;
        __syncthreads();
        if (tid == 0) {
            float s = b1[hrow];
#pragma unroll
            for (int k = 0; k < 8; ++k) s += red_lds[k];
            __hip_atomic_store(&hid[hrow], fmaxf(s, 0.0f), __ATOMIC_RELAXED,
                               __HIP_MEMORY_SCOPE_AGENT);
        }
        __syncthreads();
    }
    __threadfence();
    if (tid == 0)
        __hip_atomic_store(&flags[w * 4], T_SEQ + 2, __ATOMIC_RELAXED,
                           __HIP_MEMORY_SCOPE_AGENT);

    // ---- output layer: WG 0 only ----
    if (w == 0) {
        if (tid < 256) {
            while (__hip_atomic_load(&flags[tid * 4], __ATOMIC_RELAXED,
                                     __HIP_MEMORY_SCOPE_AGENT) < T_SEQ + 2)
                __builtin_amdgcn_s_sleep(1);
        }
        __syncthreads();
        float hv4[4];
        {
            const u64* h64 = (const u64*)hid;
            u64 a0 = __hip_atomic_load(h64 + 2 * tid,     __ATOMIC_RELAXED,
                                       __HIP_MEMORY_SCOPE_AGENT);
            u64 a1 = __hip_atomic_load(h64 + 2 * tid + 1, __ATOMIC_RELAXED,
                                       __HIP_MEMORY_SCOPE_AGENT);
            float2 f0 = *(float2*)&a0;
            float2 f1 = *(float2*)&a1;
            hv4[0] = f0.x; hv4[1] = f0.y; hv4[2] = f1.x; hv4[3] = f1.y;
        }
#pragma unroll
        for (int o = 0; o < 4; ++o) {
            float pv = 0.0f;
#pragma unroll
            for (int k = 0; k < 4; ++k)
                pv = fmaf(W2[o * HDIM + tid * 4 + k], hv4[k], pv);
#pragma unroll
            for (int m = 1; m < 64; m <<= 1) pv += __shfl_xor(pv, m, 64);
            if (lane == 0) red_lds[v] = pv;
            __syncthreads();
            if (tid == 0) {
                float s = b2[o];
#pragma unroll
                for (int k = 0; k < 8; ++k) s += red_lds[k];
                out[o] = s;
            }
            __syncthreads();
        }
    }
}

extern "C" void kernel_launch(void* const* d_in, const int* in_sizes, int n_in,
                              void* d_out, int out_size, void* d_ws, size_t ws_size,
                              hipStream_t stream) {
    const float* x     = (const float*)d_in[0];
    const float* ldist = (const float*)d_in[1];
    const float* lhead = (const float*)d_in[2];
    const float* W_ih  = (const float*)d_in[3];
    const float* W_hh  = (const float*)d_in[4];
    const float* b_ih  = (const float*)d_in[5];
    const float* b_hh  = (const float*)d_in[6];
    const float* W1    = (const float*)d_in[7];
    const float* b1    = (const float*)d_in[8];
    const float* W2    = (const float*)d_in[9];
    const float* b2    = (const float*)d_in[10];
    float* out = (float*)d_out;

    uint8_t* wsb = (uint8_t*)d_ws;
    int*   flags = (int*)wsb;
    float* hbuf  = (float*)(wsb + 4096);
    float* feat  = (float*)(wsb + 20480);
    float* hid   = (float*)(wsb + 53248);

    // allow >64KB total LDS (host-side attribute, not a stream op; R6-proven)
    static int attr_done = 0;
    if (!attr_done) {
        hipFuncSetAttribute((const void*)policy_persistent,
                            hipFuncAttributeMaxDynamicSharedMemorySize,
                            DYN_LDS_BYTES);
        attr_done = 1;
    }

    // zero flags / hbuf / feat / hid (ws is poisoned 0xAA before every launch)
    hipLaunchKernelGGL(init_ws_kernel, dim3(64), dim3(256), 0, stream, (uint32_t*)d_ws);

    void* args[] = {
        (void*)&x, (void*)&ldist, (void*)&lhead, (void*)&W_ih, (void*)&W_hh,
        (void*)&b_ih, (void*)&b_hh, (void*)&W1, (void*)&b1, (void*)&W2, (void*)&b2,
        (void*)&out, (void*)&flags, (void*)&hbuf, (void*)&feat, (void*)&hid
    };
    hipError_t e = hipLaunchCooperativeKernel((void*)policy_persistent,
                                              dim3(NB), dim3(NT), args,
                                              DYN_LDS_BYTES, stream);
    if (e != hipSuccess) {
        // fallback: normal launch — 140KB LDS/WG forces 1 WG/CU, grid == #CUs,
        // so all 256 WGs are co-resident anyway.
        hipLaunchKernelGGL(policy_persistent, dim3(NB), dim3(NT), DYN_LDS_BYTES,
                           stream,
                           x, ldist, lhead, W_ih, W_hh, b_ih, b_hh, W1, b1, W2, b2,
                           out, flags, hbuf, feat, hid);
    }
}